// Round 1
// baseline (736.038 us; speedup 1.0000x reference)
//
#include <hip/hip_runtime.h>
#include <hip/hip_bf16.h>

// SMoE: B=4 S=2048 D=1024 F=2048 E=8 K=2
#define DD 1024
#define FF 2048
#define EE 8
#define NT 8192            // B*S tokens
#define NRSEL 16384        // NT*K selected rows
#define NRCAP 16896        // NRSEL + EE*64 padding
#define MAXTILES 264       // NRCAP/64

typedef __attribute__((ext_vector_type(8))) short bf16x8;
typedef __attribute__((ext_vector_type(4))) float f32x4;

__device__ __forceinline__ ushort f2bf(float f) {
  __hip_bfloat16 h = __float2bfloat16(f);
  return *reinterpret_cast<ushort*>(&h);
}

__device__ __forceinline__ void gload16(const void* g, void* l) {
  __builtin_amdgcn_global_load_lds((const __attribute__((address_space(1))) void*)g,
                                   (__attribute__((address_space(3))) void*)l, 16, 0, 0);
}

// ---------------- weight transpose+cast: in f32 [E][R][C] -> out bf16 [E][C][R]
__global__ __launch_bounds__(256) void k_transpose(const float* __restrict__ in,
                                                   ushort* __restrict__ outT, int R, int C) {
  __shared__ float tile[32][33];
  const int e = blockIdx.z;
  const int c0 = blockIdx.x * 32, r0 = blockIdx.y * 32;
  const int tx = threadIdx.x & 31, ty = threadIdx.x >> 5;   // ty 0..7
  const float* ip = in + (size_t)e * R * C;
  #pragma unroll
  for (int i = 0; i < 4; i++)
    tile[ty + i * 8][tx] = ip[(size_t)(r0 + ty + i * 8) * C + c0 + tx];
  __syncthreads();
  ushort* op = outT + (size_t)e * C * R;
  #pragma unroll
  for (int i = 0; i < 4; i++)
    op[(size_t)(c0 + ty + i * 8) * R + r0 + tx] = f2bf(tile[tx][ty + i * 8]);
}

// ---------------- RMSNorm + gating (one block per token) ----------------
__global__ __launch_bounds__(256) void k_rms_gate(
    const float* __restrict__ x, const float* __restrict__ rms_w,
    const float* __restrict__ Wg, const float* __restrict__ bg,
    ushort* __restrict__ xn, float* __restrict__ out0, float* __restrict__ outW,
    int* __restrict__ tk_e, float* __restrict__ tk_w, int* __restrict__ counts) {
  const int t = blockIdx.x, tid = threadIdx.x;
  const int wid = tid >> 6, lane = tid & 63;
  const float4 xv = reinterpret_cast<const float4*>(x + (size_t)t * DD)[tid];
  float ss = xv.x * xv.x + xv.y * xv.y + xv.z * xv.z + xv.w * xv.w;
  #pragma unroll
  for (int m = 32; m; m >>= 1) ss += __shfl_xor(ss, m);
  __shared__ float sred[4];
  __shared__ float slog[4][8];
  if (lane == 0) sred[wid] = ss;
  __syncthreads();
  const float ms = (sred[0] + sred[1] + sred[2] + sred[3]) * (1.0f / (float)DD);
  const float sc = 1.0f / sqrtf(ms + 1.1920929e-07f);   // finfo(f32).eps
  const float4 wv = reinterpret_cast<const float4*>(rms_w)[tid];
  float xs[4] = { xv.x * sc * wv.x, xv.y * sc * wv.y, xv.z * sc * wv.z, xv.w * sc * wv.w };
  ushort4 st = make_ushort4(f2bf(xs[0]), f2bf(xs[1]), f2bf(xs[2]), f2bf(xs[3]));
  reinterpret_cast<ushort4*>(xn + (size_t)t * DD)[tid] = st;
  reinterpret_cast<float4*>(out0 + (size_t)t * DD)[tid] = make_float4(0.f, 0.f, 0.f, 0.f);
  // gating logits in fp32
  float lg[8] = {0.f, 0.f, 0.f, 0.f, 0.f, 0.f, 0.f, 0.f};
  const float4* Wg4 = reinterpret_cast<const float4*>(Wg);
  const int d = tid * 4;
  #pragma unroll
  for (int j = 0; j < 4; j++) {
    float4 wa = Wg4[(d + j) * 2];
    float4 wb = Wg4[(d + j) * 2 + 1];
    lg[0] += xs[j] * wa.x; lg[1] += xs[j] * wa.y; lg[2] += xs[j] * wa.z; lg[3] += xs[j] * wa.w;
    lg[4] += xs[j] * wb.x; lg[5] += xs[j] * wb.y; lg[6] += xs[j] * wb.z; lg[7] += xs[j] * wb.w;
  }
  #pragma unroll
  for (int m = 32; m; m >>= 1) {
    #pragma unroll
    for (int i = 0; i < 8; i++) lg[i] += __shfl_xor(lg[i], m);
  }
  if (lane == 0) {
    #pragma unroll
    for (int i = 0; i < 8; i++) slog[wid][i] = lg[i];
  }
  __syncthreads();
  if (tid == 0) {
    float l[8];
    for (int i = 0; i < 8; i++)
      l[i] = slog[0][i] + slog[1][i] + slog[2][i] + slog[3][i] + bg[i];
    int i0 = 0; float v0 = l[0];
    for (int i = 1; i < 8; i++) if (l[i] > v0) { v0 = l[i]; i0 = i; }   // first max (jax tie rule)
    int i1 = -1; float v1 = -3.4e38f;
    for (int i = 0; i < 8; i++) if (i != i0 && l[i] > v1) { v1 = l[i]; i1 = i; }
    const float e1v = __expf(v1 - v0);
    const float w0 = 1.0f / (1.0f + e1v);
    const float w1 = e1v * w0;
    float* wrow = outW + (size_t)t * EE;
    for (int i = 0; i < 8; i++) wrow[i] = 0.f;
    wrow[i0] = w0; wrow[i1] = w1;
    tk_e[t] = i0 | (i1 << 8);
    tk_w[2 * t] = w0; tk_w[2 * t + 1] = w1;
    atomicAdd(&counts[i0], 1);
    atomicAdd(&counts[i1], 1);
  }
}

// ---------------- scan counts -> 64-aligned bases; init row map ----------------
__global__ void k_scan(const int* __restrict__ counts, int* __restrict__ base,
                       int* __restrict__ cursors, int* __restrict__ tok_of_row) {
  if (threadIdx.x == 0) {
    int acc = 0;
    for (int e = 0; e < EE; e++) {
      base[e] = acc;
      cursors[e] = 0;
      acc += ((counts[e] + 63) >> 6) << 6;
    }
    base[EE] = acc;
  }
  for (int i = threadIdx.x; i < NRCAP; i += 256) tok_of_row[i] = -1;
}

// ---------------- scatter tokens into expert-grouped rows ----------------
__global__ __launch_bounds__(256) void k_scatter(
    const int* __restrict__ tk_e, const float* __restrict__ tk_w,
    const int* __restrict__ base, int* __restrict__ cursors,
    int* __restrict__ tok_of_row, float* __restrict__ gw_of_row) {
  const int t = blockIdx.x * 256 + threadIdx.x;
  if (t >= NT) return;
  const int ee = tk_e[t];
  const int e0 = ee & 255, e1 = (ee >> 8) & 255;
  int s = atomicAdd(&cursors[e0], 1);
  int row = base[e0] + s;
  tok_of_row[row] = t; gw_of_row[row] = tk_w[2 * t];
  s = atomicAdd(&cursors[e1], 1);
  row = base[e1] + s;
  tok_of_row[row] = t; gw_of_row[row] = tk_w[2 * t + 1];
}

// LDS XOR swizzle for 64-row x 64-byte tiles (breaks 8-way bank conflict,
// compatible with global_load_lds linear dest via pre-swizzled source column)
__device__ __forceinline__ int swz_of_row(int r) { return ((r >> 1) & 3) << 4; }

// ---------------- grouped GEMM1: H = silu(X@W1a + b1a) * (X@W1b + b1b) ----------------
__global__ __launch_bounds__(256) void k_ffn1(
    const ushort* __restrict__ xn, const ushort* __restrict__ W1aT, const ushort* __restrict__ W1bT,
    const float* __restrict__ b1a, const float* __restrict__ b1b,
    const int* __restrict__ tok_of_row, const int* __restrict__ base,
    ushort* __restrict__ H) {
  const int row0 = blockIdx.y * 64;
  if (row0 >= base[EE]) return;
  int e = 0;
  while (e < EE - 1 && row0 >= base[e + 1]) e++;
  const int f0 = blockIdx.x * 64;
  const int tid = threadIdx.x, wid = tid >> 6, lane = tid & 63;
  __shared__ ushort sA[64 * 32], sBa[64 * 32], sBb[64 * 32];
  // staging: thread covers 16B at linear LDS pos tid*16; source column pre-swizzled
  const int rloc = tid >> 2;
  const int cbs = ((tid & 3) * 16) ^ swz_of_row(rloc);
  const int kcol = cbs >> 1;                      // bf16 element offset, multiple of 8
  int tok = tok_of_row[row0 + rloc]; if (tok < 0) tok = 0;
  const ushort* gA  = xn   + (size_t)tok * DD + kcol;
  const ushort* gBa = W1aT + ((size_t)e * FF + f0 + rloc) * DD + kcol;
  const ushort* gBb = W1bT + ((size_t)e * FF + f0 + rloc) * DD + kcol;
  ushort* lA  = sA  + wid * 512;   // 1024B per wave
  ushort* lBa = sBa + wid * 512;
  ushort* lBb = sBb + wid * 512;
  // fragment LDS byte offsets (constant over K loop)
  const int lrow = lane & 15, q = lane >> 4;
  const int fswz = swz_of_row(lrow);
  const int aoff = (wid * 16 + lrow) * 64 + ((q * 16) ^ fswz);
  int boff[4];
  #pragma unroll
  for (int n = 0; n < 4; n++) boff[n] = (n * 16 + lrow) * 64 + ((q * 16) ^ fswz);
  f32x4 accA[4], accB[4];
  #pragma unroll
  for (int n = 0; n < 4; n++) { accA[n] = (f32x4){0.f,0.f,0.f,0.f}; accB[n] = (f32x4){0.f,0.f,0.f,0.f}; }
  for (int kt = 0; kt < DD / 32; kt++) {
    gload16(gA + kt * 32, lA);
    gload16(gBa + kt * 32, lBa);
    gload16(gBb + kt * 32, lBb);
    __syncthreads();
    const bf16x8 fa = *reinterpret_cast<const bf16x8*>(reinterpret_cast<const char*>(sA) + aoff);
    #pragma unroll
    for (int n = 0; n < 4; n++) {
      const bf16x8 fba = *reinterpret_cast<const bf16x8*>(reinterpret_cast<const char*>(sBa) + boff[n]);
      const bf16x8 fbb = *reinterpret_cast<const bf16x8*>(reinterpret_cast<const char*>(sBb) + boff[n]);
      accA[n] = __builtin_amdgcn_mfma_f32_16x16x32_bf16(fa, fba, accA[n], 0, 0, 0);
      accB[n] = __builtin_amdgcn_mfma_f32_16x16x32_bf16(fa, fbb, accB[n], 0, 0, 0);
    }
    __syncthreads();
  }
  // epilogue: h = silu(a)*b  (C/D layout: col = lane&15, row = (lane>>4)*4 + reg)
  #pragma unroll
  for (int n = 0; n < 4; n++) {
    const int f = f0 + n * 16 + lrow;
    const float ba_ = b1a[e * FF + f], bb_ = b1b[e * FF + f];
    #pragma unroll
    for (int r = 0; r < 4; r++) {
      const int grow = row0 + wid * 16 + q * 4 + r;
      const float a = accA[n][r] + ba_;
      const float b = accB[n][r] + bb_;
      const float h = (a / (1.0f + __expf(-a))) * b;
      H[(size_t)grow * FF + f] = f2bf(h);
    }
  }
}

// ---------------- grouped GEMM2: out[tok] += gw * (H@W2 + b2) ----------------
__global__ __launch_bounds__(256) void k_ffn2(
    const ushort* __restrict__ H, const ushort* __restrict__ W2T, const float* __restrict__ b2,
    const int* __restrict__ tok_of_row, const float* __restrict__ gw_of_row,
    const int* __restrict__ base, float* __restrict__ out0) {
  const int row0 = blockIdx.y * 64;
  if (row0 >= base[EE]) return;
  int e = 0;
  while (e < EE - 1 && row0 >= base[e + 1]) e++;
  const int d0 = blockIdx.x * 64;
  const int tid = threadIdx.x, wid = tid >> 6, lane = tid & 63;
  __shared__ ushort sA[64 * 32], sB[64 * 32];
  const int rloc = tid >> 2;
  const int cbs = ((tid & 3) * 16) ^ swz_of_row(rloc);
  const int kcol = cbs >> 1;
  const ushort* gA = H   + (size_t)(row0 + rloc) * FF + kcol;
  const ushort* gB = W2T + ((size_t)e * DD + d0 + rloc) * FF + kcol;
  ushort* lA = sA + wid * 512;
  ushort* lB = sB + wid * 512;
  const int lrow = lane & 15, q = lane >> 4;
  const int fswz = swz_of_row(lrow);
  const int aoff = (wid * 16 + lrow) * 64 + ((q * 16) ^ fswz);
  int boff[4];
  #pragma unroll
  for (int n = 0; n < 4; n++) boff[n] = (n * 16 + lrow) * 64 + ((q * 16) ^ fswz);
  f32x4 acc[4];
  #pragma unroll
  for (int n = 0; n < 4; n++) acc[n] = (f32x4){0.f,0.f,0.f,0.f};
  for (int kt = 0; kt < FF / 32; kt++) {
    gload16(gA + kt * 32, lA);
    gload16(gB + kt * 32, lB);
    __syncthreads();
    const bf16x8 fa = *reinterpret_cast<const bf16x8*>(reinterpret_cast<const char*>(sA) + aoff);
    #pragma unroll
    for (int n = 0; n < 4; n++) {
      const bf16x8 fb = *reinterpret_cast<const bf16x8*>(reinterpret_cast<const char*>(sB) + boff[n]);
      acc[n] = __builtin_amdgcn_mfma_f32_16x16x32_bf16(fa, fb, acc[n], 0, 0, 0);
    }
    __syncthreads();
  }
  int tokr[4]; float gwr[4];
  #pragma unroll
  for (int r = 0; r < 4; r++) {
    const int grow = row0 + wid * 16 + q * 4 + r;
    tokr[r] = tok_of_row[grow];
    gwr[r] = gw_of_row[grow];
  }
  #pragma unroll
  for (int n = 0; n < 4; n++) {
    const int dcol = d0 + n * 16 + lrow;
    const float bias = b2[e * DD + dcol];
    #pragma unroll
    for (int r = 0; r < 4; r++) {
      if (tokr[r] >= 0)
        atomicAdd(out0 + (size_t)tokr[r] * DD + dcol, gwr[r] * (acc[n][r] + bias));
    }
  }
}

// ---------------- workspace layout (bytes) ----------------
// total required: 186,880,192 bytes
#define WS_XN   ((size_t)0)                    // bf16 [NT*DD]          16,777,216
#define WS_W1AT ((size_t)16777216)             // bf16 [EE*FF*DD]       33,554,432
#define WS_W1BT ((size_t)50331648)
#define WS_W2T  ((size_t)83886080)             // bf16 [EE*DD*FF]
#define WS_H    ((size_t)117440512)            // bf16 [NRCAP*FF]       69,206,016
#define WS_TOK  ((size_t)186646528)            // int  [NRCAP]
#define WS_GW   ((size_t)186714112)            // f32  [NRCAP]
#define WS_TKE  ((size_t)186781696)            // int  [NT]
#define WS_TKW  ((size_t)186814464)            // f32  [NT*2]
#define WS_CNT  ((size_t)186880000)            // int  [8]
#define WS_BASE ((size_t)186880064)            // int  [9]
#define WS_CUR  ((size_t)186880128)            // int  [8]

extern "C" void kernel_launch(void* const* d_in, const int* in_sizes, int n_in,
                              void* d_out, int out_size, void* d_ws, size_t ws_size,
                              hipStream_t stream) {
  const float* x     = (const float*)d_in[0];
  const float* rms_w = (const float*)d_in[1];
  const float* Wg    = (const float*)d_in[2];
  const float* bg    = (const float*)d_in[3];
  const float* W1a   = (const float*)d_in[4];
  const float* b1a   = (const float*)d_in[5];
  const float* W1b   = (const float*)d_in[6];
  const float* b1b   = (const float*)d_in[7];
  const float* W2    = (const float*)d_in[8];
  const float* b2    = (const float*)d_in[9];
  float* out0 = (float*)d_out;                       // [NT*DD]
  float* outW = (float*)d_out + (size_t)NT * DD;     // [NT*EE]

  char* ws = (char*)d_ws;
  ushort* xn    = (ushort*)(ws + WS_XN);
  ushort* W1aT  = (ushort*)(ws + WS_W1AT);
  ushort* W1bT  = (ushort*)(ws + WS_W1BT);
  ushort* W2T   = (ushort*)(ws + WS_W2T);
  ushort* Hbuf  = (ushort*)(ws + WS_H);
  int*    tok   = (int*)(ws + WS_TOK);
  float*  gw    = (float*)(ws + WS_GW);
  int*    tk_e  = (int*)(ws + WS_TKE);
  float*  tk_w  = (float*)(ws + WS_TKW);
  int*    cnt   = (int*)(ws + WS_CNT);
  int*    base  = (int*)(ws + WS_BASE);
  int*    cur   = (int*)(ws + WS_CUR);

  hipMemsetAsync(cnt, 0, 8 * sizeof(int), stream);

  // weight transpose+cast (every launch; weights are inputs, never cached)
  k_transpose<<<dim3(FF / 32, DD / 32, EE), 256, 0, stream>>>(W1a, W1aT, DD, FF);
  k_transpose<<<dim3(FF / 32, DD / 32, EE), 256, 0, stream>>>(W1b, W1bT, DD, FF);
  k_transpose<<<dim3(DD / 32, FF / 32, EE), 256, 0, stream>>>(W2, W2T, FF, DD);

  k_rms_gate<<<NT, 256, 0, stream>>>(x, rms_w, Wg, bg, xn, out0, outW, tk_e, tk_w, cnt);
  k_scan<<<1, 256, 0, stream>>>(cnt, base, cur, tok);
  k_scatter<<<NT / 256, 256, 0, stream>>>(tk_e, tk_w, base, cur, tok, gw);

  k_ffn1<<<dim3(FF / 64, MAXTILES), 256, 0, stream>>>(xn, W1aT, W1bT, b1a, b1b, tok, base, Hbuf);
  k_ffn2<<<dim3(DD / 64, MAXTILES), 256, 0, stream>>>(Hbuf, W2T, b2, tok, gw, base, out0);
}

// Round 2
// 675.687 us; speedup vs baseline: 1.0893x; 1.0893x over previous
//
#include <hip/hip_runtime.h>
#include <hip/hip_bf16.h>

// SMoE: B=4 S=2048 D=1024 F=2048 E=8 K=2
#define DD 1024
#define FF 2048
#define EE 8
#define NT 8192            // B*S tokens
#define NRCAP 17280        // max 135 tiles of 128 rows (proof: sum counts = 16384 = 128*128)
#define MAXTILES 135

typedef __attribute__((ext_vector_type(8))) short bf16x8;
typedef __attribute__((ext_vector_type(4))) float f32x4;

__device__ __forceinline__ ushort f2bf(float f) {
  __hip_bfloat16 h = __float2bfloat16(f);
  return *reinterpret_cast<ushort*>(&h);
}

__device__ __forceinline__ void gload16(const void* g, void* l) {
  __builtin_amdgcn_global_load_lds((const __attribute__((address_space(1))) void*)g,
                                   (__attribute__((address_space(3))) void*)l, 16, 0, 0);
}

// LDS XOR swizzle for [rows][32 bf16] tiles: spread the 4 16B-slots of a row
// across banks by row pairs. Verified correct+conflict-reducing in round 0.
__device__ __forceinline__ int swz_of_row(int r) { return ((r >> 1) & 3) << 4; }

// ---------------- plain transpose+cast: f32 [E][R][C] -> bf16 [E][C][R]
__global__ __launch_bounds__(256) void k_transpose(const float* __restrict__ in,
                                                   ushort* __restrict__ outT, int R, int C) {
  __shared__ float tile[32][33];
  const int e = blockIdx.z;
  const int c0 = blockIdx.x * 32, r0 = blockIdx.y * 32;
  const int tx = threadIdx.x & 31, ty = threadIdx.x >> 5;   // ty 0..7
  const float* ip = in + (size_t)e * R * C;
  #pragma unroll
  for (int i = 0; i < 4; i++)
    tile[ty + i * 8][tx] = ip[(size_t)(r0 + ty + i * 8) * C + c0 + tx];
  __syncthreads();
  ushort* op = outT + (size_t)e * C * R;
  #pragma unroll
  for (int i = 0; i < 4; i++)
    op[(size_t)(c0 + ty + i * 8) * R + r0 + tx] = f2bf(tile[tx][ty + i * 8]);
}

// ---------------- interleaving transpose for W1a/W1b -> BT1 [E][4096][D] bf16
// out row for source col f: 32*(f>>4) + half*16 + (f&15)
__global__ __launch_bounds__(256) void k_transpose_pair(const float* __restrict__ in,
                                                        ushort* __restrict__ outT, int half) {
  __shared__ float tile[32][33];
  const int e = blockIdx.z;
  const int f0 = blockIdx.x * 32, d0 = blockIdx.y * 32;
  const int tx = threadIdx.x & 31, ty = threadIdx.x >> 5;
  const float* ip = in + (size_t)e * DD * FF;
  #pragma unroll
  for (int i = 0; i < 4; i++)
    tile[ty + i * 8][tx] = ip[(size_t)(d0 + ty + i * 8) * FF + f0 + tx];
  __syncthreads();
  ushort* op = outT + (size_t)e * 4096 * DD;
  #pragma unroll
  for (int i = 0; i < 4; i++) {
    const int f = f0 + ty + i * 8;
    const int r = ((f >> 4) << 5) + half * 16 + (f & 15);
    op[(size_t)r * DD + d0 + tx] = f2bf(tile[tx][ty + i * 8]);
  }
}

// ---------------- RMSNorm + gating (one block per token) ----------------
__global__ __launch_bounds__(256) void k_rms_gate(
    const float* __restrict__ x, const float* __restrict__ rms_w,
    const float* __restrict__ Wg, const float* __restrict__ bg,
    ushort* __restrict__ xn, float* __restrict__ out0, float* __restrict__ outW,
    int* __restrict__ tk_e, float* __restrict__ tk_w, int* __restrict__ counts) {
  const int t = blockIdx.x, tid = threadIdx.x;
  const int wid = tid >> 6, lane = tid & 63;
  const float4 xv = reinterpret_cast<const float4*>(x + (size_t)t * DD)[tid];
  float ss = xv.x * xv.x + xv.y * xv.y + xv.z * xv.z + xv.w * xv.w;
  #pragma unroll
  for (int m = 32; m; m >>= 1) ss += __shfl_xor(ss, m);
  __shared__ float sred[4];
  __shared__ float slog[4][8];
  if (lane == 0) sred[wid] = ss;
  __syncthreads();
  const float ms = (sred[0] + sred[1] + sred[2] + sred[3]) * (1.0f / (float)DD);
  const float sc = 1.0f / sqrtf(ms + 1.1920929e-07f);   // finfo(f32).eps
  const float4 wv = reinterpret_cast<const float4*>(rms_w)[tid];
  float xs[4] = { xv.x * sc * wv.x, xv.y * sc * wv.y, xv.z * sc * wv.z, xv.w * sc * wv.w };
  ushort4 st = make_ushort4(f2bf(xs[0]), f2bf(xs[1]), f2bf(xs[2]), f2bf(xs[3]));
  reinterpret_cast<ushort4*>(xn + (size_t)t * DD)[tid] = st;
  reinterpret_cast<float4*>(out0 + (size_t)t * DD)[tid] = make_float4(0.f, 0.f, 0.f, 0.f);
  // gating logits in fp32
  float lg[8] = {0.f, 0.f, 0.f, 0.f, 0.f, 0.f, 0.f, 0.f};
  const float4* Wg4 = reinterpret_cast<const float4*>(Wg);
  const int d = tid * 4;
  #pragma unroll
  for (int j = 0; j < 4; j++) {
    float4 wa = Wg4[(d + j) * 2];
    float4 wb = Wg4[(d + j) * 2 + 1];
    lg[0] += xs[j] * wa.x; lg[1] += xs[j] * wa.y; lg[2] += xs[j] * wa.z; lg[3] += xs[j] * wa.w;
    lg[4] += xs[j] * wb.x; lg[5] += xs[j] * wb.y; lg[6] += xs[j] * wb.z; lg[7] += xs[j] * wb.w;
  }
  #pragma unroll
  for (int m = 32; m; m >>= 1) {
    #pragma unroll
    for (int i = 0; i < 8; i++) lg[i] += __shfl_xor(lg[i], m);
  }
  if (lane == 0) {
    #pragma unroll
    for (int i = 0; i < 8; i++) slog[wid][i] = lg[i];
  }
  __syncthreads();
  if (tid == 0) {
    float l[8];
    for (int i = 0; i < 8; i++)
      l[i] = slog[0][i] + slog[1][i] + slog[2][i] + slog[3][i] + bg[i];
    int i0 = 0; float v0 = l[0];
    for (int i = 1; i < 8; i++) if (l[i] > v0) { v0 = l[i]; i0 = i; }   // first max (jax tie rule)
    int i1 = -1; float v1 = -3.4e38f;
    for (int i = 0; i < 8; i++) if (i != i0 && l[i] > v1) { v1 = l[i]; i1 = i; }
    const float e1v = __expf(v1 - v0);
    const float w0 = 1.0f / (1.0f + e1v);
    const float w1 = e1v * w0;
    float* wrow = outW + (size_t)t * EE;
    for (int i = 0; i < 8; i++) wrow[i] = 0.f;
    wrow[i0] = w0; wrow[i1] = w1;
    tk_e[t] = i0 | (i1 << 8);
    tk_w[2 * t] = w0; tk_w[2 * t + 1] = w1;
    atomicAdd(&counts[i0], 1);
    atomicAdd(&counts[i1], 1);
  }
}

// ---------------- scan counts -> 128-aligned bases; init row map ----------------
__global__ void k_scan(const int* __restrict__ counts, int* __restrict__ base,
                       int* __restrict__ cursors, int* __restrict__ tok_of_row) {
  if (threadIdx.x == 0) {
    int acc = 0;
    for (int e = 0; e < EE; e++) {
      base[e] = acc;
      cursors[e] = 0;
      acc += ((counts[e] + 127) >> 7) << 7;
    }
    base[EE] = acc;
  }
  for (int i = threadIdx.x; i < NRCAP; i += 256) tok_of_row[i] = -1;
}

// ---------------- scatter tokens into expert-grouped rows ----------------
__global__ __launch_bounds__(256) void k_scatter(
    const int* __restrict__ tk_e, const float* __restrict__ tk_w,
    const int* __restrict__ base, int* __restrict__ cursors,
    int* __restrict__ tok_of_row, float* __restrict__ gw_of_row) {
  const int t = blockIdx.x * 256 + threadIdx.x;
  if (t >= NT) return;
  const int ee = tk_e[t];
  const int e0 = ee & 255, e1 = (ee >> 8) & 255;
  int s = atomicAdd(&cursors[e0], 1);
  int row = base[e0] + s;
  tok_of_row[row] = t; gw_of_row[row] = tk_w[2 * t];
  s = atomicAdd(&cursors[e1], 1);
  row = base[e1] + s;
  tok_of_row[row] = t; gw_of_row[row] = tk_w[2 * t + 1];
}

// ---------------- grouped GEMM1 (m97 structure, 128x128 tile, BK=32) ----------------
// C = Xe @ BT1^T over interleaved N=4096; epilogue pairs (a,b) -> H = silu(a)*b
__global__ __launch_bounds__(256) void k_ffn1(
    const ushort* __restrict__ xn, const ushort* __restrict__ BT1,
    const float* __restrict__ b1a, const float* __restrict__ b1b,
    const int* __restrict__ tok_of_row, const int* __restrict__ base,
    ushort* __restrict__ H) {
  const int row0 = blockIdx.y * 128;
  if (row0 >= base[EE]) return;
  int e = 0;
  while (e < EE - 1 && row0 >= base[e + 1]) e++;
  const int c0 = blockIdx.x * 128;            // interleaved column base
  const int tid = threadIdx.x, wid = tid >> 6, lane = tid & 63;
  const int wr = wid >> 1, wc = wid & 1;      // 2x2 waves, each 64x64 output
  __shared__ ushort sA[128 * 32], sB[128 * 32];   // 8 KB each
  // staging: 2 issues per matrix; issue i covers rows i*64..i*64+63
  const int rloc = tid >> 2;                  // 0..63
  const int kcol = (((tid & 3) * 16) ^ swz_of_row(rloc)) >> 1;  // pre-swizzled src col (ushort)
  int tok0 = tok_of_row[row0 + rloc];      if (tok0 < 0) tok0 = 0;
  int tok1 = tok_of_row[row0 + 64 + rloc]; if (tok1 < 0) tok1 = 0;
  const ushort* gA0 = xn + (size_t)tok0 * DD + kcol;
  const ushort* gA1 = xn + (size_t)tok1 * DD + kcol;
  const ushort* gB0 = BT1 + ((size_t)e * 4096 + c0 + rloc) * DD + kcol;
  const ushort* gB1 = BT1 + ((size_t)e * 4096 + c0 + 64 + rloc) * DD + kcol;
  ushort* lA0 = sA + wid * 512;  ushort* lA1 = sA + 2048 + wid * 512;
  ushort* lB0 = sB + wid * 512;  ushort* lB1 = sB + 2048 + wid * 512;
  // fragment LDS byte offsets
  const int lrow = lane & 15, q = lane >> 4;
  const int fsw = (q * 16) ^ swz_of_row(lrow);
  int aoff[4], boff[4];
  #pragma unroll
  for (int m = 0; m < 4; m++) aoff[m] = (wr * 64 + m * 16 + lrow) * 64 + fsw;
  #pragma unroll
  for (int n = 0; n < 4; n++) boff[n] = (wc * 64 + n * 16 + lrow) * 64 + fsw;
  f32x4 acc[16];
  #pragma unroll
  for (int i = 0; i < 16; i++) acc[i] = (f32x4){0.f, 0.f, 0.f, 0.f};
  for (int kt = 0; kt < DD / 32; kt++) {
    gload16(gA0 + kt * 32, lA0);
    gload16(gA1 + kt * 32, lA1);
    gload16(gB0 + kt * 32, lB0);
    gload16(gB1 + kt * 32, lB1);
    __syncthreads();
    bf16x8 fb[4];
    #pragma unroll
    for (int n = 0; n < 4; n++)
      fb[n] = *reinterpret_cast<const bf16x8*>(reinterpret_cast<const char*>(sB) + boff[n]);
    #pragma unroll
    for (int m = 0; m < 4; m++) {
      const bf16x8 fa = *reinterpret_cast<const bf16x8*>(reinterpret_cast<const char*>(sA) + aoff[m]);
      #pragma unroll
      for (int n = 0; n < 4; n++)
        acc[m * 4 + n] = __builtin_amdgcn_mfma_f32_16x16x32_bf16(fa, fb[n], acc[m * 4 + n], 0, 0, 0);
    }
    __syncthreads();
  }
  // epilogue: interleaved pairs (n=2np: a-cols, n=2np+1: b-cols of same f-group)
  #pragma unroll
  for (int np = 0; np < 2; np++) {
    const int f = (c0 >> 1) + wc * 32 + np * 16 + lrow;
    const float ba_ = b1a[e * FF + f], bb_ = b1b[e * FF + f];
    #pragma unroll
    for (int m = 0; m < 4; m++) {
      #pragma unroll
      for (int r = 0; r < 4; r++) {
        const float a = acc[m * 4 + 2 * np][r] + ba_;
        const float b = acc[m * 4 + 2 * np + 1][r] + bb_;
        const float h = (a / (1.0f + __expf(-a))) * b;
        const int grow = row0 + wr * 64 + m * 16 + q * 4 + r;
        H[(size_t)grow * FF + f] = f2bf(h);
      }
    }
  }
}

// ---------------- grouped GEMM2 (m97 structure): out[tok] += gw*(H@W2 + b2) ----------------
__global__ __launch_bounds__(256) void k_ffn2(
    const ushort* __restrict__ H, const ushort* __restrict__ W2T, const float* __restrict__ b2,
    const int* __restrict__ tok_of_row, const float* __restrict__ gw_of_row,
    const int* __restrict__ base, float* __restrict__ out0) {
  const int row0 = blockIdx.y * 128;
  if (row0 >= base[EE]) return;
  int e = 0;
  while (e < EE - 1 && row0 >= base[e + 1]) e++;
  const int d0 = blockIdx.x * 128;
  const int tid = threadIdx.x, wid = tid >> 6, lane = tid & 63;
  const int wr = wid >> 1, wc = wid & 1;
  __shared__ ushort sA[128 * 32], sB[128 * 32];
  const int rloc = tid >> 2;
  const int kcol = (((tid & 3) * 16) ^ swz_of_row(rloc)) >> 1;
  const ushort* gA0 = H + (size_t)(row0 + rloc) * FF + kcol;
  const ushort* gA1 = H + (size_t)(row0 + 64 + rloc) * FF + kcol;
  const ushort* gB0 = W2T + ((size_t)e * DD + d0 + rloc) * FF + kcol;
  const ushort* gB1 = W2T + ((size_t)e * DD + d0 + 64 + rloc) * FF + kcol;
  ushort* lA0 = sA + wid * 512;  ushort* lA1 = sA + 2048 + wid * 512;
  ushort* lB0 = sB + wid * 512;  ushort* lB1 = sB + 2048 + wid * 512;
  const int lrow = lane & 15, q = lane >> 4;
  const int fsw = (q * 16) ^ swz_of_row(lrow);
  int aoff[4], boff[4];
  #pragma unroll
  for (int m = 0; m < 4; m++) aoff[m] = (wr * 64 + m * 16 + lrow) * 64 + fsw;
  #pragma unroll
  for (int n = 0; n < 4; n++) boff[n] = (wc * 64 + n * 16 + lrow) * 64 + fsw;
  f32x4 acc[16];
  #pragma unroll
  for (int i = 0; i < 16; i++) acc[i] = (f32x4){0.f, 0.f, 0.f, 0.f};
  for (int kt = 0; kt < FF / 32; kt++) {
    gload16(gA0 + kt * 32, lA0);
    gload16(gA1 + kt * 32, lA1);
    gload16(gB0 + kt * 32, lB0);
    gload16(gB1 + kt * 32, lB1);
    __syncthreads();
    bf16x8 fb[4];
    #pragma unroll
    for (int n = 0; n < 4; n++)
      fb[n] = *reinterpret_cast<const bf16x8*>(reinterpret_cast<const char*>(sB) + boff[n]);
    #pragma unroll
    for (int m = 0; m < 4; m++) {
      const bf16x8 fa = *reinterpret_cast<const bf16x8*>(reinterpret_cast<const char*>(sA) + aoff[m]);
      #pragma unroll
      for (int n = 0; n < 4; n++)
        acc[m * 4 + n] = __builtin_amdgcn_mfma_f32_16x16x32_bf16(fa, fb[n], acc[m * 4 + n], 0, 0, 0);
    }
    __syncthreads();
  }
  int tokr[4]; float gwr[4];
  #pragma unroll
  for (int m = 0; m < 4; m++) {
    const int grow = row0 + wr * 64 + m * 16 + q * 4;
    // rows q*4..q*4+3 within fragment m
    tokr[m] = grow;     // base row; tok looked up per r below
    gwr[m] = 0.f;
  }
  #pragma unroll
  for (int n = 0; n < 4; n++) {
    const int dcol = d0 + wc * 64 + n * 16 + lrow;
    const float bias = b2[e * DD + dcol];
    #pragma unroll
    for (int m = 0; m < 4; m++) {
      #pragma unroll
      for (int r = 0; r < 4; r++) {
        const int grow = row0 + wr * 64 + m * 16 + q * 4 + r;
        const int tk = tok_of_row[grow];
        if (tk >= 0)
          atomicAdd(out0 + (size_t)tk * DD + dcol, gw_of_row[grow] * (acc[m * 4 + n][r] + bias));
      }
    }
  }
}

// ---------------- workspace layout (bytes); total ~188.5 MB ----------------
#define WS_XN   ((size_t)0)                    // bf16 [NT*DD]          16,777,216
#define WS_BT1  ((size_t)16777216)             // bf16 [EE*4096*DD]     67,108,864
#define WS_W2T  ((size_t)83886080)             // bf16 [EE*DD*FF]       33,554,432
#define WS_H    ((size_t)117440512)            // bf16 [NRCAP*FF]       70,778,880
#define WS_TOK  ((size_t)188219392)            // int  [NRCAP]
#define WS_GW   ((size_t)188288512)            // f32  [NRCAP]
#define WS_TKE  ((size_t)188357632)            // int  [NT]
#define WS_TKW  ((size_t)188390400)            // f32  [NT*2]
#define WS_CNT  ((size_t)188455936)            // int  [8]
#define WS_BASE ((size_t)188456000)            // int  [9]
#define WS_CUR  ((size_t)188456064)            // int  [8]

extern "C" void kernel_launch(void* const* d_in, const int* in_sizes, int n_in,
                              void* d_out, int out_size, void* d_ws, size_t ws_size,
                              hipStream_t stream) {
  const float* x     = (const float*)d_in[0];
  const float* rms_w = (const float*)d_in[1];
  const float* Wg    = (const float*)d_in[2];
  const float* bg    = (const float*)d_in[3];
  const float* W1a   = (const float*)d_in[4];
  const float* b1a   = (const float*)d_in[5];
  const float* W1b   = (const float*)d_in[6];
  const float* b1b   = (const float*)d_in[7];
  const float* W2    = (const float*)d_in[8];
  const float* b2    = (const float*)d_in[9];
  float* out0 = (float*)d_out;                       // [NT*DD]
  float* outW = (float*)d_out + (size_t)NT * DD;     // [NT*EE]

  char* ws = (char*)d_ws;
  ushort* xn    = (ushort*)(ws + WS_XN);
  ushort* BT1   = (ushort*)(ws + WS_BT1);
  ushort* W2T   = (ushort*)(ws + WS_W2T);
  ushort* Hbuf  = (ushort*)(ws + WS_H);
  int*    tok   = (int*)(ws + WS_TOK);
  float*  gw    = (float*)(ws + WS_GW);
  int*    tk_e  = (int*)(ws + WS_TKE);
  float*  tk_w  = (float*)(ws + WS_TKW);
  int*    cnt   = (int*)(ws + WS_CNT);
  int*    base  = (int*)(ws + WS_BASE);
  int*    cur   = (int*)(ws + WS_CUR);

  hipMemsetAsync(cnt, 0, 8 * sizeof(int), stream);

  // weight transpose+cast (every launch; weights are inputs)
  k_transpose_pair<<<dim3(FF / 32, DD / 32, EE), 256, 0, stream>>>(W1a, BT1, 0);
  k_transpose_pair<<<dim3(FF / 32, DD / 32, EE), 256, 0, stream>>>(W1b, BT1, 1);
  k_transpose<<<dim3(DD / 32, FF / 32, EE), 256, 0, stream>>>(W2, W2T, FF, DD);

  k_rms_gate<<<NT, 256, 0, stream>>>(x, rms_w, Wg, bg, xn, out0, outW, tk_e, tk_w, cnt);
  k_scan<<<1, 256, 0, stream>>>(cnt, base, cur, tok);
  k_scatter<<<NT / 256, 256, 0, stream>>>(tk_e, tk_w, base, cur, tok, gw);

  k_ffn1<<<dim3(4096 / 128, MAXTILES), 256, 0, stream>>>(xn, BT1, b1a, b1b, tok, base, Hbuf);
  k_ffn2<<<dim3(DD / 128, MAXTILES), 256, 0, stream>>>(Hbuf, W2T, b2, tok, gw, base, out0);
}

// Round 3
// 621.698 us; speedup vs baseline: 1.1839x; 1.0868x over previous
//
#include <hip/hip_runtime.h>
#include <hip/hip_bf16.h>

// SMoE: B=4 S=2048 D=1024 F=2048 E=8 K=2
#define DD 1024
#define FF 2048
#define EE 8
#define NT 8192            // B*S tokens
#define NRCAP 17280        // 135 tiles of 128 rows (sum counts = 16384; <=135 tiles provable)
#define MAXTILES 135

typedef __attribute__((ext_vector_type(8))) short bf16x8;
typedef __attribute__((ext_vector_type(4))) float f32x4;

__device__ __forceinline__ ushort f2bf(float f) {
  __hip_bfloat16 h = __float2bfloat16(f);
  return *reinterpret_cast<ushort*>(&h);
}

__device__ __forceinline__ void gload16(const void* g, void* l) {
  __builtin_amdgcn_global_load_lds((const __attribute__((address_space(1))) void*)g,
                                   (__attribute__((address_space(3))) void*)l, 16, 0, 0);
}

// LDS XOR swizzle for [rows][32 bf16] tiles (verified rounds 0-2)
__device__ __forceinline__ int swz_of_row(int r) { return ((r >> 1) & 3) << 4; }

// ---------------- 64x64 vectorized transpose+cast: f32 [E][R][C] -> bf16 [E][C][R]
__global__ __launch_bounds__(256) void k_transpose64(const float* __restrict__ in,
                                                     ushort* __restrict__ outT, int R, int C) {
  __shared__ ushort tile[64][68];
  const int e = blockIdx.z;
  const int c0 = blockIdx.x * 64, r0 = blockIdx.y * 64;
  const float* ip = in + (size_t)e * R * C;
  const int cq = threadIdx.x & 15, rr = threadIdx.x >> 4;
  #pragma unroll
  for (int p = 0; p < 4; p++) {
    const int r = rr + 16 * p;
    float4 v = *reinterpret_cast<const float4*>(ip + (size_t)(r0 + r) * C + c0 + 4 * cq);
    ushort4 u = make_ushort4(f2bf(v.x), f2bf(v.y), f2bf(v.z), f2bf(v.w));
    *reinterpret_cast<ushort4*>(&tile[r][4 * cq]) = u;
  }
  __syncthreads();
  ushort* op = outT + (size_t)e * C * R;
  const int rq = threadIdx.x & 15, cc = threadIdx.x >> 4;
  #pragma unroll
  for (int p = 0; p < 4; p++) {
    const int c = cc + 16 * p;
    ushort4 u = make_ushort4(tile[4 * rq + 0][c], tile[4 * rq + 1][c],
                             tile[4 * rq + 2][c], tile[4 * rq + 3][c]);
    *reinterpret_cast<ushort4*>(op + (size_t)(c0 + c) * R + r0 + 4 * rq) = u;
  }
}

// ---------------- interleaving 64x64 transpose for W1a/W1b -> BT1 [E][4096][D]
// out row for source col f: 32*(f>>4) + half*16 + (f&15)
__global__ __launch_bounds__(256) void k_transpose_pair64(const float* __restrict__ in,
                                                          ushort* __restrict__ outT, int half) {
  __shared__ ushort tile[64][68];
  const int e = blockIdx.z;
  const int f0 = blockIdx.x * 64, d0 = blockIdx.y * 64;
  const float* ip = in + (size_t)e * DD * FF;
  const int cq = threadIdx.x & 15, rr = threadIdx.x >> 4;
  #pragma unroll
  for (int p = 0; p < 4; p++) {
    const int r = rr + 16 * p;
    float4 v = *reinterpret_cast<const float4*>(ip + (size_t)(d0 + r) * FF + f0 + 4 * cq);
    ushort4 u = make_ushort4(f2bf(v.x), f2bf(v.y), f2bf(v.z), f2bf(v.w));
    *reinterpret_cast<ushort4*>(&tile[r][4 * cq]) = u;
  }
  __syncthreads();
  ushort* op = outT + (size_t)e * 4096 * DD;
  const int rq = threadIdx.x & 15, cc = threadIdx.x >> 4;
  #pragma unroll
  for (int p = 0; p < 4; p++) {
    const int f = f0 + cc + 16 * p;
    const int rmap = ((f >> 4) << 5) + half * 16 + (f & 15);
    ushort4 u = make_ushort4(tile[4 * rq + 0][cc + 16 * p], tile[4 * rq + 1][cc + 16 * p],
                             tile[4 * rq + 2][cc + 16 * p], tile[4 * rq + 3][cc + 16 * p]);
    *reinterpret_cast<ushort4*>(op + (size_t)rmap * DD + d0 + 4 * rq) = u;
  }
}

// ---------------- RMSNorm + gating (one block per token) ----------------
__global__ __launch_bounds__(256) void k_rms_gate(
    const float* __restrict__ x, const float* __restrict__ rms_w,
    const float* __restrict__ Wg, const float* __restrict__ bg,
    ushort* __restrict__ xn, float* __restrict__ outW,
    int* __restrict__ tk_e, float* __restrict__ tk_w, int* __restrict__ counts) {
  const int t = blockIdx.x, tid = threadIdx.x;
  const int wid = tid >> 6, lane = tid & 63;
  const float4 xv = reinterpret_cast<const float4*>(x + (size_t)t * DD)[tid];
  float ss = xv.x * xv.x + xv.y * xv.y + xv.z * xv.z + xv.w * xv.w;
  #pragma unroll
  for (int m = 32; m; m >>= 1) ss += __shfl_xor(ss, m);
  __shared__ float sred[4];
  __shared__ float slog[4][8];
  if (lane == 0) sred[wid] = ss;
  __syncthreads();
  const float ms = (sred[0] + sred[1] + sred[2] + sred[3]) * (1.0f / (float)DD);
  const float sc = 1.0f / sqrtf(ms + 1.1920929e-07f);   // finfo(f32).eps
  const float4 wv = reinterpret_cast<const float4*>(rms_w)[tid];
  float xs[4] = { xv.x * sc * wv.x, xv.y * sc * wv.y, xv.z * sc * wv.z, xv.w * sc * wv.w };
  ushort4 st = make_ushort4(f2bf(xs[0]), f2bf(xs[1]), f2bf(xs[2]), f2bf(xs[3]));
  reinterpret_cast<ushort4*>(xn + (size_t)t * DD)[tid] = st;
  // gating logits in fp32
  float lg[8] = {0.f, 0.f, 0.f, 0.f, 0.f, 0.f, 0.f, 0.f};
  const float4* Wg4 = reinterpret_cast<const float4*>(Wg);
  const int d = tid * 4;
  #pragma unroll
  for (int j = 0; j < 4; j++) {
    float4 wa = Wg4[(d + j) * 2];
    float4 wb = Wg4[(d + j) * 2 + 1];
    lg[0] += xs[j] * wa.x; lg[1] += xs[j] * wa.y; lg[2] += xs[j] * wa.z; lg[3] += xs[j] * wa.w;
    lg[4] += xs[j] * wb.x; lg[5] += xs[j] * wb.y; lg[6] += xs[j] * wb.z; lg[7] += xs[j] * wb.w;
  }
  #pragma unroll
  for (int m = 32; m; m >>= 1) {
    #pragma unroll
    for (int i = 0; i < 8; i++) lg[i] += __shfl_xor(lg[i], m);
  }
  if (lane == 0) {
    #pragma unroll
    for (int i = 0; i < 8; i++) slog[wid][i] = lg[i];
  }
  __syncthreads();
  if (tid == 0) {
    float l[8];
    for (int i = 0; i < 8; i++)
      l[i] = slog[0][i] + slog[1][i] + slog[2][i] + slog[3][i] + bg[i];
    int i0 = 0; float v0 = l[0];
    for (int i = 1; i < 8; i++) if (l[i] > v0) { v0 = l[i]; i0 = i; }   // first max (jax tie rule)
    int i1 = -1; float v1 = -3.4e38f;
    for (int i = 0; i < 8; i++) if (i != i0 && l[i] > v1) { v1 = l[i]; i1 = i; }
    const float e1v = __expf(v1 - v0);
    const float w0 = 1.0f / (1.0f + e1v);
    const float w1 = e1v * w0;
    float* wrow = outW + (size_t)t * EE;
    for (int i = 0; i < 8; i++) wrow[i] = 0.f;
    wrow[i0] = w0; wrow[i1] = w1;
    tk_e[t] = i0 | (i1 << 8);
    tk_w[2 * t] = w0; tk_w[2 * t + 1] = w1;
    atomicAdd(&counts[i0], 1);
    atomicAdd(&counts[i1], 1);
  }
}

// ---------------- scan counts -> 128-aligned bases; init row map ----------------
__global__ void k_scan(const int* __restrict__ counts, int* __restrict__ base,
                       int* __restrict__ cursors, int* __restrict__ tok_of_row) {
  if (threadIdx.x == 0) {
    int acc = 0;
    for (int e = 0; e < EE; e++) {
      base[e] = acc;
      cursors[e] = 0;
      acc += ((counts[e] + 127) >> 7) << 7;
    }
    base[EE] = acc;
  }
  for (int i = threadIdx.x; i < NRCAP; i += 256) tok_of_row[i] = -1;
}

// ---------------- scatter tokens into expert-grouped rows ----------------
__global__ __launch_bounds__(256) void k_scatter(
    const int* __restrict__ tk_e, const int* __restrict__ base, int* __restrict__ cursors,
    int* __restrict__ tok_of_row, int* __restrict__ rows_of_tok) {
  const int t = blockIdx.x * 256 + threadIdx.x;
  if (t >= NT) return;
  const int ee = tk_e[t];
  const int e0 = ee & 255, e1 = (ee >> 8) & 255;
  int s = atomicAdd(&cursors[e0], 1);
  int row = base[e0] + s;
  tok_of_row[row] = t; rows_of_tok[2 * t] = row;
  s = atomicAdd(&cursors[e1], 1);
  row = base[e1] + s;
  tok_of_row[row] = t; rows_of_tok[2 * t + 1] = row;
}

// ---------------- grouped GEMM1 (m97 structure, 128x128 tile, BK=32) ----------------
// C = Xe @ BT1^T over interleaved N=4096; epilogue pairs (a,b) -> H = silu(a)*b
__global__ __launch_bounds__(256) void k_ffn1(
    const ushort* __restrict__ xn, const ushort* __restrict__ BT1,
    const float* __restrict__ b1a, const float* __restrict__ b1b,
    const int* __restrict__ tok_of_row, const int* __restrict__ base,
    ushort* __restrict__ H) {
  const int row0 = blockIdx.y * 128;
  if (row0 >= base[EE]) return;
  int e = 0;
  while (e < EE - 1 && row0 >= base[e + 1]) e++;
  const int c0 = blockIdx.x * 128;            // interleaved column base
  const int tid = threadIdx.x, wid = tid >> 6, lane = tid & 63;
  const int wr = wid >> 1, wc = wid & 1;      // 2x2 waves, each 64x64 output
  __shared__ ushort sA[128 * 32], sB[128 * 32];   // 8 KB each
  const int rloc = tid >> 2;                  // 0..63
  const int kcol = (((tid & 3) * 16) ^ swz_of_row(rloc)) >> 1;  // pre-swizzled src col
  int tok0 = tok_of_row[row0 + rloc];      if (tok0 < 0) tok0 = 0;
  int tok1 = tok_of_row[row0 + 64 + rloc]; if (tok1 < 0) tok1 = 0;
  const ushort* gA0 = xn + (size_t)tok0 * DD + kcol;
  const ushort* gA1 = xn + (size_t)tok1 * DD + kcol;
  const ushort* gB0 = BT1 + ((size_t)e * 4096 + c0 + rloc) * DD + kcol;
  const ushort* gB1 = BT1 + ((size_t)e * 4096 + c0 + 64 + rloc) * DD + kcol;
  ushort* lA0 = sA + wid * 512;  ushort* lA1 = sA + 2048 + wid * 512;
  ushort* lB0 = sB + wid * 512;  ushort* lB1 = sB + 2048 + wid * 512;
  const int lrow = lane & 15, q = lane >> 4;
  const int fsw = (q * 16) ^ swz_of_row(lrow);
  int aoff[4], boff[4];
  #pragma unroll
  for (int m = 0; m < 4; m++) aoff[m] = (wr * 64 + m * 16 + lrow) * 64 + fsw;
  #pragma unroll
  for (int n = 0; n < 4; n++) boff[n] = (wc * 64 + n * 16 + lrow) * 64 + fsw;
  f32x4 acc[16];
  #pragma unroll
  for (int i = 0; i < 16; i++) acc[i] = (f32x4){0.f, 0.f, 0.f, 0.f};
  for (int kt = 0; kt < DD / 32; kt++) {
    gload16(gA0 + kt * 32, lA0);
    gload16(gA1 + kt * 32, lA1);
    gload16(gB0 + kt * 32, lB0);
    gload16(gB1 + kt * 32, lB1);
    __syncthreads();
    bf16x8 fb[4];
    #pragma unroll
    for (int n = 0; n < 4; n++)
      fb[n] = *reinterpret_cast<const bf16x8*>(reinterpret_cast<const char*>(sB) + boff[n]);
    #pragma unroll
    for (int m = 0; m < 4; m++) {
      const bf16x8 fa = *reinterpret_cast<const bf16x8*>(reinterpret_cast<const char*>(sA) + aoff[m]);
      #pragma unroll
      for (int n = 0; n < 4; n++)
        acc[m * 4 + n] = __builtin_amdgcn_mfma_f32_16x16x32_bf16(fa, fb[n], acc[m * 4 + n], 0, 0, 0);
    }
    __syncthreads();
  }
  // epilogue: interleaved pairs (n=2np: a-cols, n=2np+1: b-cols of same f-group)
  #pragma unroll
  for (int np = 0; np < 2; np++) {
    const int f = (c0 >> 1) + wc * 32 + np * 16 + lrow;
    const float ba_ = b1a[e * FF + f], bb_ = b1b[e * FF + f];
    #pragma unroll
    for (int m = 0; m < 4; m++) {
      #pragma unroll
      for (int r = 0; r < 4; r++) {
        const float a = acc[m * 4 + 2 * np][r] + ba_;
        const float b = acc[m * 4 + 2 * np + 1][r] + bb_;
        const float h = (a / (1.0f + __expf(-a))) * b;
        const int grow = row0 + wr * 64 + m * 16 + q * 4 + r;
        H[(size_t)grow * FF + f] = f2bf(h);
      }
    }
  }
}

// ---------------- grouped GEMM2 (m97 structure): Y[row] = H@W2 + b2 (dense stores) ----------------
__global__ __launch_bounds__(256) void k_ffn2(
    const ushort* __restrict__ H, const ushort* __restrict__ W2T, const float* __restrict__ b2,
    const int* __restrict__ base, float* __restrict__ Y) {
  const int row0 = blockIdx.y * 128;
  if (row0 >= base[EE]) return;
  int e = 0;
  while (e < EE - 1 && row0 >= base[e + 1]) e++;
  const int d0 = blockIdx.x * 128;
  const int tid = threadIdx.x, wid = tid >> 6, lane = tid & 63;
  const int wr = wid >> 1, wc = wid & 1;
  __shared__ ushort sA[128 * 32], sB[128 * 32];
  const int rloc = tid >> 2;
  const int kcol = (((tid & 3) * 16) ^ swz_of_row(rloc)) >> 1;
  const ushort* gA0 = H + (size_t)(row0 + rloc) * FF + kcol;
  const ushort* gA1 = H + (size_t)(row0 + 64 + rloc) * FF + kcol;
  const ushort* gB0 = W2T + ((size_t)e * DD + d0 + rloc) * FF + kcol;
  const ushort* gB1 = W2T + ((size_t)e * DD + d0 + 64 + rloc) * FF + kcol;
  ushort* lA0 = sA + wid * 512;  ushort* lA1 = sA + 2048 + wid * 512;
  ushort* lB0 = sB + wid * 512;  ushort* lB1 = sB + 2048 + wid * 512;
  const int lrow = lane & 15, q = lane >> 4;
  const int fsw = (q * 16) ^ swz_of_row(lrow);
  int aoff[4], boff[4];
  #pragma unroll
  for (int m = 0; m < 4; m++) aoff[m] = (wr * 64 + m * 16 + lrow) * 64 + fsw;
  #pragma unroll
  for (int n = 0; n < 4; n++) boff[n] = (wc * 64 + n * 16 + lrow) * 64 + fsw;
  f32x4 acc[16];
  #pragma unroll
  for (int i = 0; i < 16; i++) acc[i] = (f32x4){0.f, 0.f, 0.f, 0.f};
  for (int kt = 0; kt < FF / 32; kt++) {
    gload16(gA0 + kt * 32, lA0);
    gload16(gA1 + kt * 32, lA1);
    gload16(gB0 + kt * 32, lB0);
    gload16(gB1 + kt * 32, lB1);
    __syncthreads();
    bf16x8 fb[4];
    #pragma unroll
    for (int n = 0; n < 4; n++)
      fb[n] = *reinterpret_cast<const bf16x8*>(reinterpret_cast<const char*>(sB) + boff[n]);
    #pragma unroll
    for (int m = 0; m < 4; m++) {
      const bf16x8 fa = *reinterpret_cast<const bf16x8*>(reinterpret_cast<const char*>(sA) + aoff[m]);
      #pragma unroll
      for (int n = 0; n < 4; n++)
        acc[m * 4 + n] = __builtin_amdgcn_mfma_f32_16x16x32_bf16(fa, fb[n], acc[m * 4 + n], 0, 0, 0);
    }
    __syncthreads();
  }
  #pragma unroll
  for (int n = 0; n < 4; n++) {
    const int dcol = d0 + wc * 64 + n * 16 + lrow;
    const float bias = b2[e * DD + dcol];
    #pragma unroll
    for (int m = 0; m < 4; m++) {
      #pragma unroll
      for (int r = 0; r < 4; r++) {
        const int grow = row0 + wr * 64 + m * 16 + q * 4 + r;
        Y[(size_t)grow * DD + dcol] = acc[m * 4 + n][r] + bias;
      }
    }
  }
}

// ---------------- gather: out[t] = w0*Y[r0] + w1*Y[r1] ----------------
__global__ __launch_bounds__(256) void k_gather(
    const float* __restrict__ Y, const int* __restrict__ rows_of_tok,
    const float* __restrict__ tk_w, float* __restrict__ out0) {
  const int t = blockIdx.x;
  const int r0 = rows_of_tok[2 * t], r1 = rows_of_tok[2 * t + 1];
  const float w0 = tk_w[2 * t], w1 = tk_w[2 * t + 1];
  const float4 y0 = reinterpret_cast<const float4*>(Y + (size_t)r0 * DD)[threadIdx.x];
  const float4 y1 = reinterpret_cast<const float4*>(Y + (size_t)r1 * DD)[threadIdx.x];
  float4 o;
  o.x = w0 * y0.x + w1 * y1.x;
  o.y = w0 * y0.y + w1 * y1.y;
  o.z = w0 * y0.z + w1 * y1.z;
  o.w = w0 * y0.w + w1 * y1.w;
  reinterpret_cast<float4*>(out0 + (size_t)t * DD)[threadIdx.x] = o;
}

// ---------------- workspace layout (bytes); total ~188.5 MB ----------------
// Y (fp32 [NRCAP*DD] = 70,778,880) aliases XN+BT1, which are dead by ffn2 time.
#define WS_Y    ((size_t)0)
#define WS_XN   ((size_t)0)                    // bf16 [NT*DD]          16,777,216
#define WS_BT1  ((size_t)16777216)             // bf16 [EE*4096*DD]     67,108,864
#define WS_W2T  ((size_t)83886080)             // bf16 [EE*DD*FF]       33,554,432
#define WS_H    ((size_t)117440512)            // bf16 [NRCAP*FF]       70,778,880
#define WS_TOK  ((size_t)188219392)            // int  [NRCAP]
#define WS_ROWS ((size_t)188288512)            // int  [2*NT]
#define WS_TKE  ((size_t)188354048)            // int  [NT]
#define WS_TKW  ((size_t)188386816)            // f32  [2*NT]
#define WS_CNT  ((size_t)188452352)            // int  [8]
#define WS_BASE ((size_t)188452416)            // int  [9]
#define WS_CUR  ((size_t)188452480)            // int  [8]

extern "C" void kernel_launch(void* const* d_in, const int* in_sizes, int n_in,
                              void* d_out, int out_size, void* d_ws, size_t ws_size,
                              hipStream_t stream) {
  const float* x     = (const float*)d_in[0];
  const float* rms_w = (const float*)d_in[1];
  const float* Wg    = (const float*)d_in[2];
  const float* bg    = (const float*)d_in[3];
  const float* W1a   = (const float*)d_in[4];
  const float* b1a   = (const float*)d_in[5];
  const float* W1b   = (const float*)d_in[6];
  const float* b1b   = (const float*)d_in[7];
  const float* W2    = (const float*)d_in[8];
  const float* b2    = (const float*)d_in[9];
  float* out0 = (float*)d_out;                       // [NT*DD]
  float* outW = (float*)d_out + (size_t)NT * DD;     // [NT*EE]

  char* ws = (char*)d_ws;
  ushort* xn    = (ushort*)(ws + WS_XN);
  ushort* BT1   = (ushort*)(ws + WS_BT1);
  ushort* W2T   = (ushort*)(ws + WS_W2T);
  ushort* Hbuf  = (ushort*)(ws + WS_H);
  float*  Ybuf  = (float*)(ws + WS_Y);
  int*    tok   = (int*)(ws + WS_TOK);
  int*    rows  = (int*)(ws + WS_ROWS);
  int*    tk_e  = (int*)(ws + WS_TKE);
  float*  tk_w  = (float*)(ws + WS_TKW);
  int*    cnt   = (int*)(ws + WS_CNT);
  int*    base  = (int*)(ws + WS_BASE);
  int*    cur   = (int*)(ws + WS_CUR);

  hipMemsetAsync(cnt, 0, 8 * sizeof(int), stream);

  // weight transpose+cast (every launch; weights are inputs)
  k_transpose_pair64<<<dim3(FF / 64, DD / 64, EE), 256, 0, stream>>>(W1a, BT1, 0);
  k_transpose_pair64<<<dim3(FF / 64, DD / 64, EE), 256, 0, stream>>>(W1b, BT1, 1);
  k_transpose64<<<dim3(DD / 64, FF / 64, EE), 256, 0, stream>>>(W2, W2T, FF, DD);

  k_rms_gate<<<NT, 256, 0, stream>>>(x, rms_w, Wg, bg, xn, outW, tk_e, tk_w, cnt);
  k_scan<<<1, 256, 0, stream>>>(cnt, base, cur, tok);
  k_scatter<<<NT / 256, 256, 0, stream>>>(tk_e, base, cur, tok, rows);

  k_ffn1<<<dim3(4096 / 128, MAXTILES), 256, 0, stream>>>(xn, BT1, b1a, b1b, tok, base, Hbuf);
  k_ffn2<<<dim3(DD / 128, MAXTILES), 256, 0, stream>>>(Hbuf, W2T, b2, base, Ybuf);
  k_gather<<<NT, 256, 0, stream>>>(Ybuf, rows, tk_w, out0);
}